// Round 8
// baseline (2538.738 us; speedup 1.0000x reference)
//
#include <hip/hip_runtime.h>
#include <math.h>

namespace {
constexpr int kS = 2048;
constexpr int kD = 64;
constexpr int kBH = 32;              // B*H = 2*16
constexpr int kTopK = 32;
constexpr int kBins = 4096;          // 12-bit radix (= sortable >> 20)
constexpr int kMaxCand = 256;        // cap for bins >= bstar-1 (~80 typical)
constexpr size_t kCtxElems  = (size_t)kBH * kS * kD;   // 4,194,304
constexpr size_t kAttnElems = (size_t)kBH * kS * kS;   // 134,217,728
}

__device__ __forceinline__ unsigned sortable_bits(float x) {
  unsigned u = __float_as_uint(x);
  return u ^ ((u & 0x80000000u) ? 0xFFFFFFFFu : 0x80000000u);
}

// ---------------------------------------------------------------------------
// Kernel 1: compute scores = Q K^T / 8 (fp32, FROZEN R4-validated chain:
// single accumulator, d strictly ascending, `acc += a*b` contracted to fma,
// *0.125f last) but emit only 16-bit monotone KEYS (sortable>>16), packed
// into the FIRST 4 KB of each attn row (row-private alias: K2 block for row
// r consumes its keys before overwriting the row). Write traffic 512->256 MB
// and K2's read becomes LLC-resident.
// ---------------------------------------------------------------------------
__global__ __launch_bounds__(256) void qk_keys(const float* __restrict__ q,
                                               const float* __restrict__ k,
                                               unsigned short* __restrict__ keys) {
  __shared__ float QsT[64][132];  // [d][q-row]
  __shared__ float KsT[64][132];  // [d][k-row]
  const int bh  = blockIdx.z;
  const int q0  = blockIdx.y * 128;
  const int k0  = blockIdx.x * 128;
  const int tid = threadIdx.x;
  const float* qg = q + ((size_t)bh * kS + q0) * kD;
  const float* kg = k + ((size_t)bh * kS + k0) * kD;

#pragma unroll
  for (int rnd = 0; rnd < 8; ++rnd) {
    int flat = rnd * 1024 + tid * 4;   // 128*64 floats per tile
    int r = flat >> 6;                 // tile row
    int c = flat & 63;                 // d
    float4 qv = *(const float4*)(qg + flat);
    QsT[c + 0][r] = qv.x;
    QsT[c + 1][r] = qv.y;
    QsT[c + 2][r] = qv.z;
    QsT[c + 3][r] = qv.w;
    float4 kv = *(const float4*)(kg + flat);
    KsT[c + 0][r] = kv.x;
    KsT[c + 1][r] = kv.y;
    KsT[c + 2][r] = kv.z;
    KsT[c + 3][r] = kv.w;
  }
  __syncthreads();

  const int ty8 = (tid >> 4) * 8;   // q rows ty8..ty8+7
  const int tx8 = (tid & 15) * 8;   // k cols tx8..tx8+7
  float acc[8][8] = {};
#pragma unroll
  for (int d4 = 0; d4 < 64; d4 += 4) {
    float a[4][8], b[4][8];
#pragma unroll
    for (int u = 0; u < 4; ++u) {
      *(float4*)(&a[u][0]) = *(const float4*)(&QsT[d4 + u][ty8]);
      *(float4*)(&a[u][4]) = *(const float4*)(&QsT[d4 + u][ty8 + 4]);
      *(float4*)(&b[u][0]) = *(const float4*)(&KsT[d4 + u][tx8]);
      *(float4*)(&b[u][4]) = *(const float4*)(&KsT[d4 + u][tx8 + 4]);
    }
    // Frozen per-element chain: d4 outer, u inner ascending.
#pragma unroll
    for (int i = 0; i < 8; ++i)
#pragma unroll
      for (int u = 0; u < 4; ++u)
#pragma unroll
        for (int j = 0; j < 8; ++j)
          acc[i][j] += a[u][i] * b[u][j];
  }

#pragma unroll
  for (int i = 0; i < 8; ++i) {
    size_t R = (size_t)bh * kS + q0 + ty8 + i;
    unsigned short* kb = keys + R * 4096 + (k0 + tx8);  // row-private 4 KB
    unsigned short t8[8];
#pragma unroll
    for (int j = 0; j < 8; ++j) {
      float s = acc[i][j] * 0.125f;
      t8[j] = (unsigned short)(sortable_bits(s) >> 16);
    }
    *(ushort4*)(kb)     = make_ushort4(t8[0], t8[1], t8[2], t8[3]);
    *(ushort4*)(kb + 4) = make_ushort4(t8[4], t8[5], t8[6], t8[7]);
  }
}

// ---------------------------------------------------------------------------
// Kernel 2: one 256-thread block per query row. Pivot from the u16-key
// histogram (bins = key>>4 = sortable>>20, identical to R5-R7). Candidates =
// bins >= bstar-1 (guard). Exact fp32 scores RECOMPUTED for candidates only
// (same `acc += a*b`, d-ascending chain as K1 -> same bits). Selection:
// t32 = 32nd-largest fp32 VALUE (dups counted), keep = score >= t32.
// ---------------------------------------------------------------------------
__global__ __launch_bounds__(256) void topk_softmax(const float* __restrict__ q,
                                                    const float* __restrict__ k,
                                                    const float* __restrict__ v,
                                                    float* __restrict__ ctx,
                                                    float* __restrict__ attn,
                                                    float* __restrict__ mask) {
  const int row  = blockIdx.x;     // bh*2048 + qi
  const int bh   = row >> 11;
  const int tid  = threadIdx.x;
  const int lane = tid & 63;
  const int wid  = tid >> 6;

  __shared__ unsigned s_hist[kBins];       // 16 KB
  __shared__ float    s_q[kD];
  __shared__ int      s_cidx[kMaxCand];
  __shared__ float    s_cval[kMaxCand];
  __shared__ float    s_w[kMaxCand];
  __shared__ unsigned s_T[4];
  __shared__ unsigned s_nc;
  __shared__ int      s_bstar;
  __shared__ float    s_t32, s_mx, s_Z;

  // P0: load keys (row-private prefix of the attn row) + zero hist + stage q.
  const unsigned short* keyrow = (const unsigned short*)attn + (size_t)row * 4096;
  ushort4 ka = *(const ushort4*)(keyrow + tid * 4);
  ushort4 kb = *(const ushort4*)(keyrow + 1024 + tid * 4);
  unsigned keys8[8] = {ka.x, ka.y, ka.z, ka.w, kb.x, kb.y, kb.z, kb.w};
  int      loce[8];
  unsigned bins[8];
#pragma unroll
  for (int j = 0; j < 8; ++j) {
    loce[j] = (j < 4) ? (tid * 4 + j) : (1024 + tid * 4 + (j - 4));
    bins[j] = keys8[j] >> 4;
  }
#pragma unroll
  for (int i = 0; i < 4; ++i)
    *(uint4*)(&s_hist[tid * 16 + i * 4]) = make_uint4(0u, 0u, 0u, 0u);
  if (tid == 0) s_nc = 0u;
  if (tid < 16)
    *(float4*)(&s_q[tid * 4]) = *(const float4*)(q + (size_t)row * kD + tid * 4);
  __syncthreads();

  // P1: histogram.
#pragma unroll
  for (int j = 0; j < 8; ++j) atomicAdd(&s_hist[bins[j]], 1u);
  __syncthreads();

  // P2: chunk sums (16 bins/thread) + in-wave suffix scan via shfl.
  unsigned lsum = 0;
#pragma unroll
  for (int j = 0; j < 16; ++j) lsum += s_hist[tid * 16 + j];
  unsigned sfx = lsum;
#pragma unroll
  for (int off = 1; off < 64; off <<= 1) {
    unsigned z = __shfl_down(sfx, off);
    if (lane + off < 64) sfx += z;
  }
  if (lane == 0) s_T[wid] = sfx;
  __syncthreads();

  // P3: global suffix -> pivot bin bstar.
  unsigned hi = 0;
#pragma unroll
  for (int w = 0; w < 4; ++w)
    if (w > wid) hi += s_T[w];
  unsigned gsfx  = sfx + hi;
  unsigned above = gsfx - lsum;
  if (gsfx >= (unsigned)kTopK && above < (unsigned)kTopK) {
    unsigned run = above;
    for (int j = 15; j >= 0; --j) {
      unsigned h = s_hist[tid * 16 + j];
      if (run < (unsigned)kTopK && run + h >= (unsigned)kTopK)
        s_bstar = tid * 16 + j;
      run += h;
    }
  }
  __syncthreads();
  const int blo = s_bstar - 1;   // 1 guard bin below pivot

  // P4: collect candidate indices (bins >= blo; superset of true top-32).
#pragma unroll
  for (int j = 0; j < 8; ++j) {
    if ((int)bins[j] >= blo) {
      unsigned pos = atomicAdd(&s_nc, 1u);
      if (pos < (unsigned)kMaxCand) s_cidx[pos] = loce[j];
    }
  }
  __syncthreads();
  const int m = (int)min(s_nc, (unsigned)kMaxCand);

  // P5: recompute exact fp32 scores for candidates (same chain as K1:
  // single acc, d ascending, contracted fma, *0.125f last).
  for (int c = tid; c < m; c += 256) {
    const float* kr = k + ((size_t)bh * kS + s_cidx[c]) * kD;
    float acc = 0.0f;
    for (int d = 0; d < kD; ++d) acc += s_q[d] * kr[d];
    s_cval[c] = acc * 0.125f;
  }
  __syncthreads();

  // P6: exact (g,e) ranking -> t32 (32nd-largest value) and max.
  for (int c = tid; c < m; c += 256) {
    float x = s_cval[c];
    int g = 0, e = 0;
    for (int j2 = 0; j2 < m; ++j2) {
      float y = s_cval[j2];
      g += (y > x);
      e += (y == x);
    }
    if (g == 0) s_mx = x;
    if (g < kTopK && g + e >= kTopK) s_t32 = x;
  }
  __syncthreads();
  const float t32 = s_t32;
  const float mx  = s_mx;

  // P7: weights.
  for (int c = tid; c < m; c += 256)
    s_w[c] = (s_cval[c] >= t32) ? __expf(s_cval[c] - mx) : 0.0f;
  __syncthreads();
  if (tid == 0) {
    float z = 0.0f;
    for (int c2 = 0; c2 < m; ++c2) z += s_w[c2];
    s_Z = z;
  }
  __syncthreads();
  const float invZ = 1.0f / s_Z;

  // P8: per-element outputs. bins < blo: definitely masked. bins >= blo:
  // candidate — look up its weight (w==0 -> masked).
  float a8[8], m8[8];
#pragma unroll
  for (int j = 0; j < 8; ++j) {
    float av = 0.0f, mv = 1.0f;
    if ((int)bins[j] >= blo) {
      float w = 0.0f;
      for (int c = 0; c < m; ++c)
        if (s_cidx[c] == loce[j]) { w = s_w[c]; break; }
      if (w > 0.0f) { av = w * invZ; mv = 0.0f; }
    }
    a8[j] = av; m8[j] = mv;
  }
  float* arow = attn + (size_t)row * kS;   // overwrites the key prefix — keys
  float* mrow = mask + (size_t)row * kS;   // already consumed into registers
  *(float4*)(arow + tid * 4)        = make_float4(a8[0], a8[1], a8[2], a8[3]);
  *(float4*)(arow + 1024 + tid * 4) = make_float4(a8[4], a8[5], a8[6], a8[7]);
  *(float4*)(mrow + tid * 4)        = make_float4(m8[0], m8[1], m8[2], m8[3]);
  *(float4*)(mrow + 1024 + tid * 4) = make_float4(m8[4], m8[5], m8[6], m8[7]);

  // P9: context (wave 0, lane = d; coalesced v reads over ~32 kept rows).
  if (tid < kD) {
    float acc = 0.0f;
    for (int c = 0; c < m; ++c)
      if (s_w[c] > 0.0f)
        acc += s_w[c] * v[((size_t)bh * kS + s_cidx[c]) * kD + tid];
    ctx[(size_t)row * kD + tid] = acc * invZ;
  }
}

extern "C" void kernel_launch(void* const* d_in, const int* in_sizes, int n_in,
                              void* d_out, int out_size, void* d_ws, size_t ws_size,
                              hipStream_t stream) {
  const float* q = (const float*)d_in[0];
  const float* k = (const float*)d_in[1];
  const float* v = (const float*)d_in[2];
  float* out  = (float*)d_out;
  float* ctx  = out;
  float* attn = out + kCtxElems;
  float* mask = attn + kAttnElems;

  dim3 g1(kS / 128, kS / 128, kBH);
  qk_keys<<<g1, 256, 0, stream>>>(q, k, (unsigned short*)attn);
  topk_softmax<<<dim3(kBH * kS), 256, 0, stream>>>(q, k, v, ctx, attn, mask);
}

// Round 9
// 1894.052 us; speedup vs baseline: 1.3404x; 1.3404x over previous
//
#include <hip/hip_runtime.h>
#include <math.h>

namespace {
constexpr int kS = 2048;
constexpr int kD = 64;
constexpr int kBH = 32;              // B*H = 2*16
constexpr int kTopK = 32;
constexpr int kBins = 1024;          // 10-bit radix (= sortable >> 22)
constexpr int kMaxCand = 512;        // cap for bins >= bstar (~50 typical)
constexpr size_t kCtxElems  = (size_t)kBH * kS * kD;   // 4,194,304
constexpr size_t kAttnElems = (size_t)kBH * kS * kS;   // 134,217,728
}

__device__ __forceinline__ unsigned sortable_bits(float x) {
  unsigned u = __float_as_uint(x);
  return u ^ ((u & 0x80000000u) ? 0xFFFFFFFFu : 0x80000000u);
}

// ---------------------------------------------------------------------------
// Kernel 1 (unchanged from R8): scores = Q K^T / 8 with the FROZEN
// R4-validated chain (single fp32 accumulator, d strictly ascending,
// `acc += a*b` contracted to fma, *0.125f last); emits 16-bit monotone keys
// (sortable>>16) into the first 4 KB of each attn row (row-private alias).
// ---------------------------------------------------------------------------
__global__ __launch_bounds__(256) void qk_keys(const float* __restrict__ q,
                                               const float* __restrict__ k,
                                               unsigned short* __restrict__ keys) {
  __shared__ float QsT[64][132];  // [d][q-row]
  __shared__ float KsT[64][132];  // [d][k-row]
  const int bh  = blockIdx.z;
  const int q0  = blockIdx.y * 128;
  const int k0  = blockIdx.x * 128;
  const int tid = threadIdx.x;
  const float* qg = q + ((size_t)bh * kS + q0) * kD;
  const float* kg = k + ((size_t)bh * kS + k0) * kD;

#pragma unroll
  for (int rnd = 0; rnd < 8; ++rnd) {
    int flat = rnd * 1024 + tid * 4;   // 128*64 floats per tile
    int r = flat >> 6;                 // tile row
    int c = flat & 63;                 // d
    float4 qv = *(const float4*)(qg + flat);
    QsT[c + 0][r] = qv.x;
    QsT[c + 1][r] = qv.y;
    QsT[c + 2][r] = qv.z;
    QsT[c + 3][r] = qv.w;
    float4 kv = *(const float4*)(kg + flat);
    KsT[c + 0][r] = kv.x;
    KsT[c + 1][r] = kv.y;
    KsT[c + 2][r] = kv.z;
    KsT[c + 3][r] = kv.w;
  }
  __syncthreads();

  const int ty8 = (tid >> 4) * 8;   // q rows ty8..ty8+7
  const int tx8 = (tid & 15) * 8;   // k cols tx8..tx8+7
  float acc[8][8] = {};
#pragma unroll
  for (int d4 = 0; d4 < 64; d4 += 4) {
    float a[4][8], b[4][8];
#pragma unroll
    for (int u = 0; u < 4; ++u) {
      *(float4*)(&a[u][0]) = *(const float4*)(&QsT[d4 + u][ty8]);
      *(float4*)(&a[u][4]) = *(const float4*)(&QsT[d4 + u][ty8 + 4]);
      *(float4*)(&b[u][0]) = *(const float4*)(&KsT[d4 + u][tx8]);
      *(float4*)(&b[u][4]) = *(const float4*)(&KsT[d4 + u][tx8 + 4]);
    }
    // Frozen per-element chain: d4 outer, u inner ascending.
#pragma unroll
    for (int i = 0; i < 8; ++i)
#pragma unroll
      for (int u = 0; u < 4; ++u)
#pragma unroll
        for (int j = 0; j < 8; ++j)
          acc[i][j] += a[u][i] * b[u][j];
  }

#pragma unroll
  for (int i = 0; i < 8; ++i) {
    size_t R = (size_t)bh * kS + q0 + ty8 + i;
    unsigned short* kb = keys + R * 4096 + (k0 + tx8);  // row-private 4 KB
    unsigned short t8[8];
#pragma unroll
    for (int j = 0; j < 8; ++j) {
      float s = acc[i][j] * 0.125f;
      t8[j] = (unsigned short)(sortable_bits(s) >> 16);
    }
    *(ushort4*)(kb)     = make_ushort4(t8[0], t8[1], t8[2], t8[3]);
    *(ushort4*)(kb + 4) = make_ushort4(t8[4], t8[5], t8[6], t8[7]);
  }
}

// ---------------------------------------------------------------------------
// Kernel 2 v3: one 256-thread block per query row.
//  - 1024-bin key histogram -> pivot bin bstar (4 KB LDS).
//  - candidates = bins >= bstar, NO guard (keys are a monotone coarsening of
//    score order: score>=t32 => key>=key(t32) => bin>=bstar; ties share bins).
//  - exact fp32 recompute for candidates only (frozen sequential-d chain,
//    same bits as K1) -> exact (g,e) rank -> t32.
//  - weights SCATTERED into pre-zeroed s_attn[2048]; vectorized readback
//    writes attn (= w*invZ) and mask (= w>0 ? 0 : 1). No per-element search.
// ---------------------------------------------------------------------------
__global__ __launch_bounds__(256) void topk_softmax(const float* __restrict__ q,
                                                    const float* __restrict__ k,
                                                    const float* __restrict__ v,
                                                    float* __restrict__ ctx,
                                                    float* __restrict__ attn,
                                                    float* __restrict__ mask) {
  const int row  = blockIdx.x;     // bh*2048 + qi
  const int bh   = row >> 11;
  const int tid  = threadIdx.x;
  const int lane = tid & 63;
  const int wid  = tid >> 6;

  __shared__ unsigned s_hist[kBins];       // 4 KB
  __shared__ float    s_attn[kS];          // 8 KB (raw weights, 0 = masked)
  __shared__ float    s_q[kD];
  __shared__ int      s_cidx[kMaxCand];    // 2 KB
  __shared__ float    s_cval[kMaxCand];    // 2 KB
  __shared__ float    s_w[kMaxCand];       // 2 KB
  __shared__ float    s_wsum[4];
  __shared__ unsigned s_T[4];
  __shared__ unsigned s_nc;
  __shared__ int      s_bstar;
  __shared__ float    s_t32, s_mx;

  // P0: load keys (row-private prefix of the attn row), zero hist + s_attn,
  // stage q.
  const unsigned short* keyrow = (const unsigned short*)attn + (size_t)row * 4096;
  ushort4 ka = *(const ushort4*)(keyrow + tid * 4);
  ushort4 kb = *(const ushort4*)(keyrow + 1024 + tid * 4);
  unsigned keys8[8] = {ka.x, ka.y, ka.z, ka.w, kb.x, kb.y, kb.z, kb.w};
  int      loce[8];
  unsigned bins[8];
#pragma unroll
  for (int j = 0; j < 8; ++j) {
    loce[j] = (j < 4) ? (tid * 4 + j) : (1024 + tid * 4 + (j - 4));
    bins[j] = keys8[j] >> 6;          // = sortable >> 22
  }
  *(uint4*)(&s_hist[tid * 4]) = make_uint4(0u, 0u, 0u, 0u);
  *(float4*)(&s_attn[tid * 4])        = make_float4(0.f, 0.f, 0.f, 0.f);
  *(float4*)(&s_attn[1024 + tid * 4]) = make_float4(0.f, 0.f, 0.f, 0.f);
  if (tid == 0) s_nc = 0u;
  if (tid < 16)
    *(float4*)(&s_q[tid * 4]) = *(const float4*)(q + (size_t)row * kD + tid * 4);
  __syncthreads();

  // P1: histogram.
#pragma unroll
  for (int j = 0; j < 8; ++j) atomicAdd(&s_hist[bins[j]], 1u);
  __syncthreads();

  // P2: chunk sums (4 bins/thread) + in-wave suffix scan via shfl.
  unsigned lsum = 0;
#pragma unroll
  for (int j = 0; j < 4; ++j) lsum += s_hist[tid * 4 + j];
  unsigned sfx = lsum;
#pragma unroll
  for (int off = 1; off < 64; off <<= 1) {
    unsigned z = __shfl_down(sfx, off);
    if (lane + off < 64) sfx += z;
  }
  if (lane == 0) s_T[wid] = sfx;
  __syncthreads();

  // P3: global suffix -> pivot bin bstar.
  unsigned hi = 0;
#pragma unroll
  for (int w = 0; w < 4; ++w)
    if (w > wid) hi += s_T[w];
  unsigned gsfx  = sfx + hi;
  unsigned above = gsfx - lsum;
  if (gsfx >= (unsigned)kTopK && above < (unsigned)kTopK) {
    unsigned run = above;
    for (int j = 3; j >= 0; --j) {
      unsigned h = s_hist[tid * 4 + j];
      if (run < (unsigned)kTopK && run + h >= (unsigned)kTopK)
        s_bstar = tid * 4 + j;
      run += h;
    }
  }
  __syncthreads();
  const int bstar = s_bstar;

  // P4: collect candidate indices (bins >= bstar; exact superset of keep-set).
#pragma unroll
  for (int j = 0; j < 8; ++j) {
    if ((int)bins[j] >= bstar) {
      unsigned pos = atomicAdd(&s_nc, 1u);
      if (pos < (unsigned)kMaxCand) s_cidx[pos] = loce[j];
    }
  }
  __syncthreads();
  const int m = (int)min(s_nc, (unsigned)kMaxCand);

  // P5: recompute exact fp32 scores for candidates (frozen chain: single
  // acc, d ascending, contracted fma, *0.125f last).
  for (int c = tid; c < m; c += 256) {
    const float* kr = k + ((size_t)bh * kS + s_cidx[c]) * kD;
    float acc = 0.0f;
    for (int d = 0; d < kD; ++d) acc += s_q[d] * kr[d];
    s_cval[c] = acc * 0.125f;
  }
  __syncthreads();

  // P6: exact (g,e) ranking -> t32 (32nd-largest value, dups counted) + max.
  for (int c = tid; c < m; c += 256) {
    float x = s_cval[c];
    int g = 0, e = 0;
    for (int j2 = 0; j2 < m; ++j2) {
      float y = s_cval[j2];
      g += (y > x);
      e += (y == x);
    }
    if (g == 0) s_mx = x;
    if (g < kTopK && g + e >= kTopK) s_t32 = x;
  }
  __syncthreads();
  const float t32 = s_t32;
  const float mx  = s_mx;

  // P7: weights; scatter raw w into s_attn; parallel Z reduce.
  float psum = 0.0f;
  for (int c = tid; c < m; c += 256) {
    float cv = s_cval[c];
    float wv = (cv >= t32) ? __expf(cv - mx) : 0.0f;
    s_w[c] = wv;
    psum += wv;
    if (wv > 0.0f) s_attn[s_cidx[c]] = wv;   // unique indices, no conflict
  }
#pragma unroll
  for (int off = 32; off >= 1; off >>= 1)
    psum += __shfl_xor(psum, off);
  if (lane == 0) s_wsum[wid] = psum;
  __syncthreads();
  const float Z = s_wsum[0] + s_wsum[1] + s_wsum[2] + s_wsum[3];
  const float invZ = 1.0f / Z;

  // P8: vectorized readback -> attn and mask writes (mask = w>0 ? 0 : 1;
  // kept weights are >= exp(t32-mx) > 0, never flushed to zero).
  float4 w0 = *(const float4*)(&s_attn[tid * 4]);
  float4 w1 = *(const float4*)(&s_attn[1024 + tid * 4]);
  float* arow = attn + (size_t)row * kS;   // overwrites key prefix (consumed)
  float* mrow = mask + (size_t)row * kS;
  *(float4*)(arow + tid * 4) =
      make_float4(w0.x * invZ, w0.y * invZ, w0.z * invZ, w0.w * invZ);
  *(float4*)(arow + 1024 + tid * 4) =
      make_float4(w1.x * invZ, w1.y * invZ, w1.z * invZ, w1.w * invZ);
  *(float4*)(mrow + tid * 4) =
      make_float4(w0.x > 0.f ? 0.f : 1.f, w0.y > 0.f ? 0.f : 1.f,
                  w0.z > 0.f ? 0.f : 1.f, w0.w > 0.f ? 0.f : 1.f);
  *(float4*)(mrow + 1024 + tid * 4) =
      make_float4(w1.x > 0.f ? 0.f : 1.f, w1.y > 0.f ? 0.f : 1.f,
                  w1.z > 0.f ? 0.f : 1.f, w1.w > 0.f ? 0.f : 1.f);

  // P9: context (wave 0, lane = d; coalesced v reads over ~32 kept rows).
  if (tid < kD) {
    float acc = 0.0f;
    for (int c = 0; c < m; ++c)
      if (s_w[c] > 0.0f)
        acc += s_w[c] * v[((size_t)bh * kS + s_cidx[c]) * kD + tid];
    ctx[(size_t)row * kD + tid] = acc * invZ;
  }
}

extern "C" void kernel_launch(void* const* d_in, const int* in_sizes, int n_in,
                              void* d_out, int out_size, void* d_ws, size_t ws_size,
                              hipStream_t stream) {
  const float* q = (const float*)d_in[0];
  const float* k = (const float*)d_in[1];
  const float* v = (const float*)d_in[2];
  float* out  = (float*)d_out;
  float* ctx  = out;
  float* attn = out + kCtxElems;
  float* mask = attn + kAttnElems;

  dim3 g1(kS / 128, kS / 128, kBH);
  qk_keys<<<g1, 256, 0, stream>>>(q, k, (unsigned short*)attn);
  topk_softmax<<<dim3(kBH * kS), 256, 0, stream>>>(q, k, v, ctx, attn, mask);
}